// Round 1
// baseline (93.425 us; speedup 1.0000x reference)
//
#include <hip/hip_runtime.h>

// Problem constants (match reference)
#define HH 256
#define WW 512
#define NB 128
#define N_STUFF 11
#define N_SEG 19

constexpr int W4       = WW / 4;                 // 128 float4 groups per row
constexpr int STUFF_N4 = N_STUFF * HH * W4;      // 360448
constexpr int INST_N4  = NB * HH * W4;           // 4194304
constexpr int TOTAL_N4 = STUFF_N4 + INST_N4;     // 4554752

__global__ __launch_bounds__(256)
void SegTerm_70248485093641_kernel(const int* __restrict__ cls,
                                   const float4* __restrict__ seg4,
                                   const float* __restrict__ boxes,
                                   float4* __restrict__ out)
{
    const int idx = blockIdx.x * 256 + threadIdx.x;
    if (idx >= TOTAL_N4) return;

    if (idx < STUFF_N4) {
        // Output 0: straight copy of the first 11 channels.
        out[idx] = seg4[idx];
        return;
    }

    // Output 1: instance energy.
    const int t   = idx - STUFF_N4;
    const int box = t >> 15;        // / (HH * W4) = 32768
    const int rem = t & 32767;
    const int y   = rem >> 7;       // / W4
    const int xg  = rem & (W4 - 1);
    const int x   = xg << 2;

    float4 v = make_float4(0.f, 0.f, 0.f, 0.f);

    const int c = cls[box];
    if (c != 0) {
        // b = boxes[:,1:] * 0.25 (exact in fp32)
        const float by0 = boxes[box * 5 + 2] * 0.25f;
        const float by1 = boxes[box * 5 + 4] * 0.25f;
        const int y0 = (int)floorf(by0);
        const int y1 = (int)(rintf(by1) + 1.0f);   // jnp.round = RNE -> rintf

        if (y >= y0 && y < y1) {
            const float bx0 = boxes[box * 5 + 1] * 0.25f;
            const float bx1 = boxes[box * 5 + 3] * 0.25f;
            const int x0 = (int)floorf(bx0);
            const int x1 = (int)(rintf(bx1) + 1.0f);

            int mapped = c + 10;
            if (mapped > N_SEG - 1) mapped = N_SEG - 1;

            const int src_base = (mapped * HH + y) * W4;
            if (x >= x0 && x + 3 < x1) {
                // fully-interior group: aligned float4 gather
                v = seg4[src_base + xg];
            } else if (x + 3 >= x0 && x < x1) {
                // boundary group: per-element mask
                const float* src = (const float*)seg4 + (size_t)src_base * 4 + x;
                float e[4];
                #pragma unroll
                for (int j = 0; j < 4; ++j) {
                    const int xx = x + j;
                    e[j] = (xx >= x0 && xx < x1) ? src[j] : 0.f;
                }
                v = make_float4(e[0], e[1], e[2], e[3]);
            }
        }
    }

    out[idx] = v;
}

extern "C" void kernel_launch(void* const* d_in, const int* in_sizes, int n_in,
                              void* d_out, int out_size, void* d_ws, size_t ws_size,
                              hipStream_t stream) {
    const int*    cls   = (const int*)d_in[0];
    const float4* seg4  = (const float4*)d_in[1];
    const float*  boxes = (const float*)d_in[2];
    float4*       out   = (float4*)d_out;

    const int blocks = (TOTAL_N4 + 255) / 256;   // 17792
    SegTerm_70248485093641_kernel<<<blocks, 256, 0, stream>>>(cls, seg4, boxes, out);
}